// Round 2
// baseline (370.172 us; speedup 1.0000x reference)
//
#include <hip/hip_runtime.h>
#include <hip/hip_fp16.h>
#include <cstdint>
#include <cstddef>

#define B_ 4
#define S_ 4096
#define D_ 1024
#define E_ 1536
#define M_ (B_*S_)       // 16384
#define BE_ (B_*E_)      // 6144
#define C_ 32            // scan chunks
#define L_ (S_/C_)       // 128

typedef short bf16x8 __attribute__((ext_vector_type(8)));
typedef float f32x4 __attribute__((ext_vector_type(4)));

__device__ __forceinline__ unsigned short f2b(float f) {
  union { float f; unsigned int i; } x; x.f = f;
  unsigned int r = x.i + 0x7FFFu + ((x.i >> 16) & 1u);   // RNE
  return (unsigned short)(r >> 16);
}
__device__ __forceinline__ float h2f(unsigned short u) { return __half2float(__ushort_as_half(u)); }
__device__ __forceinline__ unsigned int packcv(float c, float v) {
  return (unsigned int)__half_as_ushort(__float2half_rn(c)) |
         ((unsigned int)__half_as_ushort(__float2half_rn(v)) << 16);
}
__device__ __forceinline__ void async16(const unsigned short* g, unsigned short* l) {
  __builtin_amdgcn_global_load_lds((const __attribute__((address_space(1))) unsigned int*)g,
                                   (__attribute__((address_space(3))) unsigned int*)l, 16, 0, 0);
}

// ---------- fp32 -> bf16 conversion, generic (1024 elems / block) ----------
__global__ __launch_bounds__(256) void cvt_bf16(const float* __restrict__ src,
                                                unsigned short* __restrict__ dst) {
  const int i = blockIdx.x * 256 + threadIdx.x;
  float4 f = ((const float4*)src)[i];
  ushort4 u; u.x = f2b(f.x); u.y = f2b(f.y); u.z = f2b(f.z); u.w = f2b(f.w);
  ((ushort4*)dst)[i] = u;
}

// ---------- fused conversion: x + W_hg ----------
#define NB_X   (M_*D_/1024)        // 16384 blocks
#define NB_WHG (2*E_*D_/1024)      // 3072
__global__ __launch_bounds__(256) void cvt_xw(const float* __restrict__ x, unsigned short* __restrict__ xb,
                                              const float* __restrict__ whg, unsigned short* __restrict__ wb) {
  int blk = blockIdx.x;
  const float* src; unsigned short* dst;
  if (blk < NB_X) { src = x; dst = xb; }
  else            { blk -= NB_X; src = whg; dst = wb; }
  const int i = blk * 256 + threadIdx.x;
  float4 f = ((const float4*)src)[i];
  ushort4 u; u.x = f2b(f.x); u.y = f2b(f.y); u.z = f2b(f.z); u.w = f2b(f.w);
  ((ushort4*)dst)[i] = u;
}

// stage 6 chunks (per-wave share of one 48KB K-tile: A 32KB + B 16KB)
#define STAGE6(buf, koff) do { _Pragma("unroll") \
  for (int j_ = 0; j_ < 6; ++j_) async16(gs[j_] + (koff), (buf) + lo[j_]); } while (0)

// ---------- GEMM1: 8 waves, tile 256m x 64e x {h,g}, BK=64, 3-buffer counted-vmcnt pipeline ----------
// LDS per buffer: A 256x64 (16384 us) + B 128x64 (8192 us) = 24576 us; 3 bufs = 144KB.
// Staging: 48 chunks of 1KB (8 rows x 8 x 16B); wave wv issues chunks wv*6 .. wv*6+5.
// chunk c<32 -> A rows [c*8,c*8+8); else B row rloc=(c-32)*8+srow: rloc<64 -> h (Wb n0+rloc),
// else g (Wb E_+n0+rloc-64).  T2 swizzle via pre-swizzled global column (scs = scol^srow),
// ds_read XORs (lm&7).  Pipeline: prefetch distance 2, one s_waitcnt vmcnt(6) + one s_barrier
// per K-tile (never drain except last tile); mod-3 rotation keeps read/write buffers distinct.
// Epilogue additionally computes the per-chunk scan summaries P,Qf,Qr (fused scan_p1):
// tile = exactly 2 chunks of 128 m; packed CV staged to LDS, segment-reduced.
__global__ __launch_bounds__(512) void gemm1_mfma(const unsigned short* __restrict__ Xb,
                                                  const unsigned short* __restrict__ Wb,
                                                  unsigned int* __restrict__ CV,
                                                  float* __restrict__ Pd,
                                                  float* __restrict__ Qfd,
                                                  float* __restrict__ Qrd) {
  __shared__ unsigned short sm[3 * 24576];   // 144KB
  const int t = threadIdx.x;
  const int m0 = blockIdx.x * 256;
  const int n0 = blockIdx.y * 64;
  const int wv = t >> 6, lane = t & 63;
  const int wm = wv >> 1, we = wv & 1;       // wm 0..3 (64m each), we 0..1 (32e each)
  const int lm = lane & 15, kg = lane >> 4;
  const int srow = lane >> 3;
  const int scs = (lane & 7) ^ srow;         // swizzled source 16B-column (srow==row&7)

  const unsigned short* gs[6]; int lo[6];
#pragma unroll
  for (int j = 0; j < 6; ++j) {
    const int c = wv * 6 + j;
    if (c < 32) {
      gs[j] = Xb + (size_t)(m0 + c * 8 + srow) * D_ + scs * 8;
      lo[j] = c * 512;
    } else {
      const int rloc = (c - 32) * 8 + srow;
      const int gr = (rloc < 64) ? (n0 + rloc) : (E_ + n0 + rloc - 64);
      gs[j] = Wb + (size_t)gr * D_ + scs * 8;
      lo[j] = 16384 + (c - 32) * 512;
    }
  }

  const f32x4 z4 = {0.f, 0.f, 0.f, 0.f};
  f32x4 ah[4][2], ag[4][2];
#pragma unroll
  for (int i = 0; i < 4; ++i)
#pragma unroll
    for (int j = 0; j < 2; ++j) { ah[i][j] = z4; ag[i][j] = z4; }

  unsigned short *rd = sm, *nx = sm + 24576, *sp = sm + 49152;
  STAGE6(rd, 0);
  STAGE6(nx, 64);
  const int NT = D_ / 64;   // 16
  for (int kt = 0; kt < NT; ++kt) {
    if (kt < NT - 1) asm volatile("s_waitcnt vmcnt(6)" ::: "memory");
    else             asm volatile("s_waitcnt vmcnt(0)" ::: "memory");
    __builtin_amdgcn_s_barrier();
    __builtin_amdgcn_sched_barrier(0);
    if (kt + 2 < NT) STAGE6(sp, (kt + 2) * 64);
#pragma unroll
    for (int kh = 0; kh < 2; ++kh) {
      const int cb = ((((kh << 2) | kg) ^ (lm & 7)) << 3);
      bf16x8 af[4], bh[2], bg[2];
#pragma unroll
      for (int mt = 0; mt < 4; ++mt)
        af[mt] = *(const bf16x8*)(rd + (size_t)(wm * 64 + mt * 16 + lm) * 64 + cb);
#pragma unroll
      for (int et = 0; et < 2; ++et) {
        bh[et] = *(const bf16x8*)(rd + 16384 + (size_t)(we * 32 + et * 16 + lm) * 64 + cb);
        bg[et] = *(const bf16x8*)(rd + 16384 + (size_t)(64 + we * 32 + et * 16 + lm) * 64 + cb);
      }
      __builtin_amdgcn_s_setprio(1);
#pragma unroll
      for (int mt = 0; mt < 4; ++mt)
#pragma unroll
        for (int et = 0; et < 2; ++et) {
          ah[mt][et] = __builtin_amdgcn_mfma_f32_16x16x32_bf16(af[mt], bh[et], ah[mt][et], 0, 0, 0);
          ag[mt][et] = __builtin_amdgcn_mfma_f32_16x16x32_bf16(af[mt], bg[et], ag[mt][et], 0, 0, 0);
        }
      __builtin_amdgcn_s_setprio(0);
    }
    unsigned short* tp = rd; rd = nx; nx = sp; sp = tp;
  }

  __syncthreads();                            // all waves done; LDS buffers free
  // epilogue: pointwise gate + pack, store CV, and stage packed into LDS [256m][64e]
  unsigned int* sc = (unsigned int*)sm;       // 64KB
#pragma unroll
  for (int mt = 0; mt < 4; ++mt)
#pragma unroll
    for (int et = 0; et < 2; ++et) {
      const int eloc = we * 32 + et * 16 + lm;
      const int e = n0 + eloc;
#pragma unroll
      for (int r = 0; r < 4; ++r) {
        const int mloc = wm * 64 + mt * 16 + kg * 4 + r;
        const float hid = ah[mt][et][r];
        const float gat = ag[mt][et][r];
        const float z = 1.f / (1.f + __expf(-gat));
        const float cc = 1.f - z;
        const float gv = (hid >= 0.f) ? (hid + 0.5f) : (1.f / (1.f + __expf(-hid)));
        const unsigned int pk = packcv(cc, z * gv);
        CV[(size_t)(m0 + mloc) * E_ + e] = pk;
        sc[mloc * 64 + eloc] = pk;
      }
    }
  __syncthreads();
  // fused scan_p1: per-thread 32-row segment reduce (e = t&63, seg = t>>6; 8 segs over 256 m)
  const int er = t & 63, seg = t >> 6;
  float pp = 1.f, qf = 0.f, qr = 0.f;
#pragma unroll 8
  for (int l = 0; l < 32; ++l) {
    const unsigned int p = sc[(seg * 32 + l) * 64 + er];
    const float c = h2f((unsigned short)p), v = h2f((unsigned short)(p >> 16));
    qf = fmaf(c, qf, v);
    qr = fmaf(pp, v, qr);
    pp *= c;
  }
  __syncthreads();                            // all sc reads done before overwrite
  float* red = (float*)sm;                    // 8 segs x 64 e x 3 floats = 6KB
  red[(seg * 64 + er) * 3 + 0] = pp;
  red[(seg * 64 + er) * 3 + 1] = qf;
  red[(seg * 64 + er) * 3 + 2] = qr;
  __syncthreads();
  if (t < 128) {                              // chunk ch = t>>6 (2 chunks), e = t&63
    const int e = t & 63, ch = t >> 6;
    float Pv = 1.f, Qfv = 0.f, Qrv = 0.f;
#pragma unroll
    for (int s = 0; s < 4; ++s) {
      const int sg = ch * 4 + s;
      const float ps  = red[(sg * 64 + e) * 3 + 0];
      const float qfs = red[(sg * 64 + e) * 3 + 1];
      const float qrs = red[(sg * 64 + e) * 3 + 2];
      Qfv = fmaf(ps, Qfv, qfs);
      Qrv = fmaf(Pv, qrs, Qrv);
      Pv *= ps;
    }
    const int kk = ((m0 & (S_ - 1)) >> 7) + ch;
    const int be = (m0 >> 12) * E_ + n0 + e;
    Pd [(size_t)kk * BE_ + be] = Pv;
    Qfd[(size_t)kk * BE_ + be] = Qfv;
    Qrd[(size_t)kk * BE_ + be] = Qrv;
  }
}

// ---------- scan pass 2: chunk-level prefix (preloaded, fully unrolled) ----------
__global__ __launch_bounds__(256) void scan_p2(const float* __restrict__ P, const float* __restrict__ Qf,
                                               const float* __restrict__ Qr, float* __restrict__ HfIn,
                                               float* __restrict__ HbIn) {
  const int be = blockIdx.x * 256 + threadIdx.x;
  float Pk[C_], Qk[C_];
#pragma unroll
  for (int k = 0; k < C_; ++k) { Pk[k] = P[(size_t)k * BE_ + be]; Qk[k] = Qf[(size_t)k * BE_ + be]; }
  float hf = 0.f;
#pragma unroll
  for (int k = 0; k < C_; ++k) {
    HfIn[(size_t)k * BE_ + be] = hf;
    hf = fmaf(Pk[k], hf, Qk[k]);
  }
#pragma unroll
  for (int k = 0; k < C_; ++k) Qk[k] = Qr[(size_t)k * BE_ + be];
  float hb = 0.f;
#pragma unroll
  for (int k = C_ - 1; k >= 0; --k) {
    HbIn[(size_t)k * BE_ + be] = hb;
    hb = fmaf(Pk[k], hb, Qk[k]);
  }
}

// ---------- scan pass 3: replay with carry-ins, write H = hf + hb (bf16) ----------
__global__ __launch_bounds__(256) void scan_p3(const unsigned int* __restrict__ CV,
                                               const float* __restrict__ HfIn,
                                               const float* __restrict__ HbIn,
                                               unsigned short* __restrict__ Hb) {
  const int be = blockIdx.x * 256 + threadIdx.x;
  const int b = be / E_, e = be - b * E_;
  const int k = blockIdx.y;
  const unsigned int* cvf = CV + ((size_t)b * S_ + (size_t)k * L_) * E_ + e;
  const unsigned int* cvb = CV + ((size_t)b * S_ + (size_t)(S_ - 1 - k * L_)) * E_ + e;
  unsigned short* hp = Hb + ((size_t)b * S_ + (size_t)k * L_) * E_ + e;
  float hf = HfIn[(size_t)k * BE_ + be];
  float hb = HbIn[(size_t)(C_ - 1 - k) * BE_ + be];
#pragma unroll 8
  for (int l = 0; l < L_; ++l) {
    const unsigned int pf = cvf[(size_t)l * E_];
    const unsigned int pb = *(cvb - (ptrdiff_t)l * E_);
    hf = fmaf(h2f((unsigned short)pf), hf, h2f((unsigned short)(pf >> 16)));
    hb = fmaf(h2f((unsigned short)pb), hb, h2f((unsigned short)(pb >> 16)));
    hp[(size_t)l * E_] = f2b(hf + hb);
  }
}

// ---------- GEMM2: 8 waves, tile 256m x 128d, BK=64, same 3-buffer pipeline ----------
// out[m,d] = sum_e H[m,e]*Wo[d,e].  chunk c<32 -> A rows (Hb), else B rows (Wob).
__global__ __launch_bounds__(512) void gemm2_mfma(const unsigned short* __restrict__ Hb,
                                                  const unsigned short* __restrict__ Wob,
                                                  float* __restrict__ Out) {
  __shared__ unsigned short sm[3 * 24576];   // 144KB
  const int t = threadIdx.x;
  const int m0 = blockIdx.x * 256;
  const int n0 = blockIdx.y * 128;
  const int wv = t >> 6, lane = t & 63;
  const int wm = wv >> 1, wn = wv & 1;       // wm 0..3 (64m), wn 0..1 (64d)
  const int lm = lane & 15, kg = lane >> 4;
  const int srow = lane >> 3;
  const int scs = (lane & 7) ^ srow;

  const unsigned short* gs[6]; int lo[6];
#pragma unroll
  for (int j = 0; j < 6; ++j) {
    const int c = wv * 6 + j;
    if (c < 32) {
      gs[j] = Hb + (size_t)(m0 + c * 8 + srow) * E_ + scs * 8;
      lo[j] = c * 512;
    } else {
      gs[j] = Wob + (size_t)(n0 + (c - 32) * 8 + srow) * E_ + scs * 8;
      lo[j] = 16384 + (c - 32) * 512;
    }
  }

  const f32x4 z4 = {0.f, 0.f, 0.f, 0.f};
  f32x4 acc[4][4];
#pragma unroll
  for (int i = 0; i < 4; ++i)
#pragma unroll
    for (int j = 0; j < 4; ++j) acc[i][j] = z4;

  unsigned short *rd = sm, *nx = sm + 24576, *sp = sm + 49152;
  STAGE6(rd, 0);
  STAGE6(nx, 64);
  const int NT = E_ / 64;   // 24
  for (int kt = 0; kt < NT; ++kt) {
    if (kt < NT - 1) asm volatile("s_waitcnt vmcnt(6)" ::: "memory");
    else             asm volatile("s_waitcnt vmcnt(0)" ::: "memory");
    __builtin_amdgcn_s_barrier();
    __builtin_amdgcn_sched_barrier(0);
    if (kt + 2 < NT) STAGE6(sp, (kt + 2) * 64);
#pragma unroll
    for (int kh = 0; kh < 2; ++kh) {
      const int cb = ((((kh << 2) | kg) ^ (lm & 7)) << 3);
      bf16x8 af[4], bfr[4];
#pragma unroll
      for (int mt = 0; mt < 4; ++mt)
        af[mt] = *(const bf16x8*)(rd + (size_t)(wm * 64 + mt * 16 + lm) * 64 + cb);
#pragma unroll
      for (int nt = 0; nt < 4; ++nt)
        bfr[nt] = *(const bf16x8*)(rd + 16384 + (size_t)(wn * 64 + nt * 16 + lm) * 64 + cb);
      __builtin_amdgcn_s_setprio(1);
#pragma unroll
      for (int mt = 0; mt < 4; ++mt)
#pragma unroll
        for (int nt = 0; nt < 4; ++nt)
          acc[mt][nt] = __builtin_amdgcn_mfma_f32_16x16x32_bf16(af[mt], bfr[nt], acc[mt][nt], 0, 0, 0);
      __builtin_amdgcn_s_setprio(0);
    }
    unsigned short* tp = rd; rd = nx; nx = sp; sp = tp;
  }
#pragma unroll
  for (int mt = 0; mt < 4; ++mt)
#pragma unroll
    for (int nt = 0; nt < 4; ++nt) {
      const int d = n0 + wn * 64 + nt * 16 + lm;
#pragma unroll
      for (int r = 0; r < 4; ++r) {
        const int m = m0 + wm * 64 + mt * 16 + kg * 4 + r;
        Out[(size_t)m * D_ + d] = acc[mt][nt][r];
      }
    }
}

extern "C" void kernel_launch(void* const* d_in, const int* in_sizes, int n_in,
                              void* d_out, int out_size, void* d_ws, size_t ws_size,
                              hipStream_t stream) {
  const float* x    = (const float*)d_in[0];
  const float* whg  = (const float*)d_in[1];
  const float* wout = (const float*)d_in[2];
  float* out = (float*)d_out;

  // ws: [CV: M*E*4][H: M*E*2]
  unsigned int*  CV = (unsigned int*)d_ws;
  unsigned short* Hb = (unsigned short*)((char*)d_ws + (size_t)M_ * E_ * 4);
  unsigned short* Xb  = Hb;                     // bf16 X in H region until scan writes H
  unsigned short* Wb  = Xb + (size_t)M_ * D_;
  unsigned short* Wob = (unsigned short*)d_ws;  // bf16 W_out in CV region — ONLY after scans done
  // scan chunk scratch in d_out (gemm2 fully overwrites)
  float* P    = out;
  float* Qf   = out + (size_t)C_ * BE_;
  float* Qr   = out + 2 * (size_t)C_ * BE_;
  float* HfIn = out + 3 * (size_t)C_ * BE_;
  float* HbIn = out + 4 * (size_t)C_ * BE_;

  cvt_xw<<<NB_X + NB_WHG, 256, 0, stream>>>(x, Xb, whg, Wb);
  gemm1_mfma<<<dim3(M_ / 256, E_ / 64), 512, 0, stream>>>(Xb, Wb, CV, P, Qf, Qr);
  scan_p2<<<BE_ / 256, 256, 0, stream>>>(P, Qf, Qr, HfIn, HbIn);
  scan_p3<<<dim3(BE_ / 256, C_), 256, 0, stream>>>(CV, HfIn, HbIn, Hb);
  cvt_bf16<<<D_ * E_ / 1024, 256, 0, stream>>>(wout, Wob);   // CV dead now
  gemm2_mfma<<<dim3(M_ / 256, D_ / 128), 512, 0, stream>>>(Hb, Wob, out);
}

// Round 3
// 343.493 us; speedup vs baseline: 1.0777x; 1.0777x over previous
//
#include <hip/hip_runtime.h>
#include <hip/hip_fp16.h>
#include <cstdint>
#include <cstddef>

#define B_ 4
#define S_ 4096
#define D_ 1024
#define E_ 1536
#define M_ (B_*S_)       // 16384
#define BE_ (B_*E_)      // 6144
#define C_ 32            // scan chunks
#define L_ (S_/C_)       // 128

typedef short bf16x8 __attribute__((ext_vector_type(8)));
typedef float f32x4 __attribute__((ext_vector_type(4)));

__device__ __forceinline__ unsigned short f2b(float f) {
  union { float f; unsigned int i; } x; x.f = f;
  unsigned int r = x.i + 0x7FFFu + ((x.i >> 16) & 1u);   // RNE
  return (unsigned short)(r >> 16);
}
__device__ __forceinline__ float h2f(unsigned short u) { return __half2float(__ushort_as_half(u)); }
__device__ __forceinline__ unsigned int packcv(float c, float v) {
  return (unsigned int)__half_as_ushort(__float2half_rn(c)) |
         ((unsigned int)__half_as_ushort(__float2half_rn(v)) << 16);
}
__device__ __forceinline__ void async16(const unsigned short* g, unsigned short* l) {
  __builtin_amdgcn_global_load_lds((const __attribute__((address_space(1))) unsigned int*)g,
                                   (__attribute__((address_space(3))) unsigned int*)l, 16, 0, 0);
}

// ---------- fp32 -> bf16 conversion, generic (1024 elems / block) ----------
__global__ __launch_bounds__(256) void cvt_bf16(const float* __restrict__ src,
                                                unsigned short* __restrict__ dst) {
  const int i = blockIdx.x * 256 + threadIdx.x;
  float4 f = ((const float4*)src)[i];
  ushort4 u; u.x = f2b(f.x); u.y = f2b(f.y); u.z = f2b(f.z); u.w = f2b(f.w);
  ((ushort4*)dst)[i] = u;
}

// ---------- fused conversion: x + W_hg (W_out must wait until CV is dead) ----------
#define NB_X   (M_*D_/1024)        // 16384 blocks
#define NB_WHG (2*E_*D_/1024)      // 3072
__global__ __launch_bounds__(256) void cvt_xw(const float* __restrict__ x, unsigned short* __restrict__ xb,
                                              const float* __restrict__ whg, unsigned short* __restrict__ wb) {
  int blk = blockIdx.x;
  const float* src; unsigned short* dst;
  if (blk < NB_X) { src = x; dst = xb; }
  else            { blk -= NB_X; src = whg; dst = wb; }
  const int i = blk * 256 + threadIdx.x;
  float4 f = ((const float4*)src)[i];
  ushort4 u; u.x = f2b(f.x); u.y = f2b(f.y); u.z = f2b(f.z); u.w = f2b(f.w);
  ((ushort4*)dst)[i] = u;
}

// ---------- GEMM1 (proven 870 TF structure: 256 thr, 32KB LDS, 2-barrier loop, T2 swizzle)
// + fused gate pointwise + fused scan_p1 (validated in round 2, identical numerics).
// tile: 128 m x 64 e; B tile = 64 h-rows + 64 g-rows. 4 waves: each 64m x 32e x {h,g}.
// Staging: waves 0,1 -> A half-tiles; waves 2,3 -> B (h / g half).
// Each wave: 8 chunks of 1KB (8 rows x 128B); lane -> row=lane>>3, 16B-col=lane&7.
// T2 swizzle: source column pre-permuted (scs=scol^srow, row&7==srow), ds_read XORs (lm&7).
// Epilogue: m-tile == one scan chunk (L_=128); packed CV staged to LDS [128m][64e] (32KB,
// exactly lA+lB), 4x32-row segment reduce, serial combine, write P/Qf/Qr.
__global__ __launch_bounds__(256) void gemm1_mfma(const unsigned short* __restrict__ Xb,
                                                  const unsigned short* __restrict__ Wb,
                                                  unsigned int* __restrict__ CV,
                                                  float* __restrict__ Pd,
                                                  float* __restrict__ Qfd,
                                                  float* __restrict__ Qrd) {
  __shared__ unsigned short sm[2 * 128 * 64];   // 32KB total: lA = sm, lB = sm + 8192
  unsigned short* lA = sm;
  unsigned short* lB = sm + 8192;
  const int t = threadIdx.x;
  const int m0 = blockIdx.x * 128;
  const int n0 = blockIdx.y * 64;
  const int wv = t >> 6, lane = t & 63;
  const int wm = wv >> 1, we = wv & 1;
  const int lm = lane & 15, kg = lane >> 4;
  const int srow = lane >> 3;
  const int scs = (lane & 7) ^ srow;            // swizzled source 16B-column
  const bool stageA = (wv < 2);
  const unsigned short* gbase;
  if (stageA) {
    gbase = Xb + (size_t)(m0 + (wv * 64) + srow) * D_ + scs * 8;
  } else {
    const int rloc = (wv - 2) * 64 + srow;      // 0..7 -> h rows, 64..71 -> g rows
    const int gr = (rloc < 64) ? (n0 + rloc) : (E_ + n0 + rloc - 64);
    gbase = Wb + (size_t)gr * D_ + scs * 8;
  }
  unsigned short* lbase = (stageA ? lA : lB) + (size_t)(wv & 1) * 4096;

  const f32x4 z4 = {0.f, 0.f, 0.f, 0.f};
  f32x4 ah[4][2], ag[4][2];
#pragma unroll
  for (int i = 0; i < 4; ++i)
#pragma unroll
    for (int j = 0; j < 2; ++j) { ah[i][j] = z4; ag[i][j] = z4; }

  for (int k0 = 0; k0 < D_; k0 += 64) {
#pragma unroll
    for (int j = 0; j < 8; ++j)
      async16(gbase + k0 + (size_t)(j * 8) * D_, lbase + (size_t)j * 512);
    __syncthreads();
#pragma unroll
    for (int kh = 0; kh < 2; ++kh) {
      const int cb = ((((kh << 2) | kg) ^ (lm & 7)) << 3);   // swizzled col (ushort units)
      bf16x8 af[4], bh[2], bg[2];
#pragma unroll
      for (int mt = 0; mt < 4; ++mt)
        af[mt] = *(const bf16x8*)(lA + (size_t)(wm * 64 + mt * 16 + lm) * 64 + cb);
#pragma unroll
      for (int et = 0; et < 2; ++et) {
        bh[et] = *(const bf16x8*)(lB + (size_t)(we * 32 + et * 16 + lm) * 64 + cb);
        bg[et] = *(const bf16x8*)(lB + (size_t)(64 + we * 32 + et * 16 + lm) * 64 + cb);
      }
#pragma unroll
      for (int mt = 0; mt < 4; ++mt)
#pragma unroll
        for (int et = 0; et < 2; ++et) {
          ah[mt][et] = __builtin_amdgcn_mfma_f32_16x16x32_bf16(af[mt], bh[et], ah[mt][et], 0, 0, 0);
          ag[mt][et] = __builtin_amdgcn_mfma_f32_16x16x32_bf16(af[mt], bg[et], ag[mt][et], 0, 0, 0);
        }
    }
    __syncthreads();
  }

  // epilogue: pointwise gate + pack; store CV; stage packed into LDS [128m][64e]
  unsigned int* sc = (unsigned int*)sm;         // 32KB, exactly lA+lB
#pragma unroll
  for (int mt = 0; mt < 4; ++mt)
#pragma unroll
    for (int et = 0; et < 2; ++et) {
      const int eloc = we * 32 + et * 16 + lm;
      const int e = n0 + eloc;
#pragma unroll
      for (int r = 0; r < 4; ++r) {
        const int mloc = wm * 64 + mt * 16 + kg * 4 + r;
        const float hid = ah[mt][et][r];
        const float gat = ag[mt][et][r];
        const float z = 1.f / (1.f + __expf(-gat));
        const float cc = 1.f - z;
        const float gv = (hid >= 0.f) ? (hid + 0.5f) : (1.f / (1.f + __expf(-hid)));
        const unsigned int pk = packcv(cc, z * gv);
        CV[(size_t)(m0 + mloc) * E_ + e] = pk;
        sc[mloc * 64 + eloc] = pk;
      }
    }
  __syncthreads();
  // fused scan_p1: 4 segments of 32 m; thread -> e = t&63, seg = t>>6
  const int er = t & 63, seg = t >> 6;
  float pp = 1.f, qf = 0.f, qr = 0.f;
#pragma unroll 8
  for (int l = 0; l < 32; ++l) {
    const unsigned int p = sc[(seg * 32 + l) * 64 + er];
    const float c = h2f((unsigned short)p), v = h2f((unsigned short)(p >> 16));
    qf = fmaf(c, qf, v);
    qr = fmaf(pp, v, qr);
    pp *= c;
  }
  __syncthreads();                              // all sc reads done before overwrite
  float* red = (float*)sm;                      // 4 segs x 64 e x 3 floats = 3KB
  red[(seg * 64 + er) * 3 + 0] = pp;
  red[(seg * 64 + er) * 3 + 1] = qf;
  red[(seg * 64 + er) * 3 + 2] = qr;
  __syncthreads();
  if (t < 64) {                                 // one chunk per block; e = t
    const int e = t;
    float Pv = 1.f, Qfv = 0.f, Qrv = 0.f;
#pragma unroll
    for (int s = 0; s < 4; ++s) {
      const float ps  = red[(s * 64 + e) * 3 + 0];
      const float qfs = red[(s * 64 + e) * 3 + 1];
      const float qrs = red[(s * 64 + e) * 3 + 2];
      Qfv = fmaf(ps, Qfv, qfs);
      Qrv = fmaf(Pv, qrs, Qrv);
      Pv *= ps;
    }
    const int kk = (m0 & (S_ - 1)) >> 7;        // chunk index within batch
    const int be = (m0 >> 12) * E_ + n0 + e;    // b*E_ + e
    Pd [(size_t)kk * BE_ + be] = Pv;
    Qfd[(size_t)kk * BE_ + be] = Qfv;
    Qrd[(size_t)kk * BE_ + be] = Qrv;
  }
}

// ---------- scan pass 2: chunk-level prefix (preloaded, fully unrolled) ----------
__global__ __launch_bounds__(256) void scan_p2(const float* __restrict__ P, const float* __restrict__ Qf,
                                               const float* __restrict__ Qr, float* __restrict__ HfIn,
                                               float* __restrict__ HbIn) {
  const int be = blockIdx.x * 256 + threadIdx.x;
  float Pk[C_], Qk[C_];
#pragma unroll
  for (int k = 0; k < C_; ++k) { Pk[k] = P[(size_t)k * BE_ + be]; Qk[k] = Qf[(size_t)k * BE_ + be]; }
  float hf = 0.f;
#pragma unroll
  for (int k = 0; k < C_; ++k) {
    HfIn[(size_t)k * BE_ + be] = hf;
    hf = fmaf(Pk[k], hf, Qk[k]);
  }
#pragma unroll
  for (int k = 0; k < C_; ++k) Qk[k] = Qr[(size_t)k * BE_ + be];
  float hb = 0.f;
#pragma unroll
  for (int k = C_ - 1; k >= 0; --k) {
    HbIn[(size_t)k * BE_ + be] = hb;   // state after consuming original chunks > k
    hb = fmaf(Pk[k], hb, Qk[k]);
  }
}

// ---------- scan pass 3: replay with carry-ins, write H = hf + hb (bf16) ----------
__global__ __launch_bounds__(256) void scan_p3(const unsigned int* __restrict__ CV,
                                               const float* __restrict__ HfIn,
                                               const float* __restrict__ HbIn,
                                               unsigned short* __restrict__ Hb) {
  const int be = blockIdx.x * 256 + threadIdx.x;
  const int b = be / E_, e = be - b * E_;
  const int k = blockIdx.y;
  const unsigned int* cvf = CV + ((size_t)b * S_ + (size_t)k * L_) * E_ + e;
  const unsigned int* cvb = CV + ((size_t)b * S_ + (size_t)(S_ - 1 - k * L_)) * E_ + e;
  unsigned short* hp = Hb + ((size_t)b * S_ + (size_t)k * L_) * E_ + e;
  float hf = HfIn[(size_t)k * BE_ + be];
  float hb = HbIn[(size_t)(C_ - 1 - k) * BE_ + be];
#pragma unroll 8
  for (int l = 0; l < L_; ++l) {
    const unsigned int pf = cvf[(size_t)l * E_];
    const unsigned int pb = *(cvb - (ptrdiff_t)l * E_);
    hf = fmaf(h2f((unsigned short)pf), hf, h2f((unsigned short)(pf >> 16)));
    hb = fmaf(h2f((unsigned short)pb), hb, h2f((unsigned short)(pb >> 16)));
    hp[(size_t)l * E_] = f2b(hf + hb);
  }
}

// ---------- GEMM2 (proven structure: 256 thr, BK=64, async staging, T2 swizzle) ----------
// out[m,d] = sum_e H[m,e]*Wo[d,e].  tile 128m x 128d; 4 waves each 64m x 64d.
__global__ __launch_bounds__(256) void gemm2_mfma(const unsigned short* __restrict__ Hb,
                                                  const unsigned short* __restrict__ Wob,
                                                  float* __restrict__ Out) {
  __shared__ unsigned short lA[128 * 64];   // 16KB
  __shared__ unsigned short lB[128 * 64];   // 16KB
  const int t = threadIdx.x;
  const int m0 = blockIdx.x * 128;
  const int n0 = blockIdx.y * 128;
  const int wv = t >> 6, lane = t & 63;
  const int wm = wv >> 1, wn = wv & 1;
  const int lm = lane & 15, kg = lane >> 4;
  const int srow = lane >> 3;
  const int scs = (lane & 7) ^ srow;        // swizzled source 16B-column
  const bool stageA = (wv < 2);
  const unsigned short* gbase;
  if (stageA) gbase = Hb  + (size_t)(m0 + wv * 64 + srow) * E_ + scs * 8;
  else        gbase = Wob + (size_t)(n0 + (wv - 2) * 64 + srow) * E_ + scs * 8;
  unsigned short* lbase = (stageA ? lA : lB) + (size_t)(wv & 1) * 4096;

  const f32x4 z4 = {0.f, 0.f, 0.f, 0.f};
  f32x4 acc[4][4];
#pragma unroll
  for (int i = 0; i < 4; ++i)
#pragma unroll
    for (int j = 0; j < 4; ++j) acc[i][j] = z4;

  for (int k0 = 0; k0 < E_; k0 += 64) {
#pragma unroll
    for (int j = 0; j < 8; ++j)
      async16(gbase + k0 + (size_t)(j * 8) * E_, lbase + (size_t)j * 512);
    __syncthreads();
#pragma unroll
    for (int kh = 0; kh < 2; ++kh) {
      const int cb = ((((kh << 2) | kg) ^ (lm & 7)) << 3);   // swizzled col (ushort units)
      bf16x8 af[4], bfr[4];
#pragma unroll
      for (int mt = 0; mt < 4; ++mt)
        af[mt] = *(const bf16x8*)(lA + (size_t)(wm * 64 + mt * 16 + lm) * 64 + cb);
#pragma unroll
      for (int nt = 0; nt < 4; ++nt)
        bfr[nt] = *(const bf16x8*)(lB + (size_t)(wn * 64 + nt * 16 + lm) * 64 + cb);
#pragma unroll
      for (int mt = 0; mt < 4; ++mt)
#pragma unroll
        for (int nt = 0; nt < 4; ++nt)
          acc[mt][nt] = __builtin_amdgcn_mfma_f32_16x16x32_bf16(af[mt], bfr[nt], acc[mt][nt], 0, 0, 0);
    }
    __syncthreads();
  }
#pragma unroll
  for (int mt = 0; mt < 4; ++mt)
#pragma unroll
    for (int nt = 0; nt < 4; ++nt) {
      const int d = n0 + wn * 64 + nt * 16 + lm;
#pragma unroll
      for (int r = 0; r < 4; ++r) {
        const int m = m0 + wm * 64 + mt * 16 + kg * 4 + r;
        Out[(size_t)m * D_ + d] = acc[mt][nt][r];
      }
    }
}

extern "C" void kernel_launch(void* const* d_in, const int* in_sizes, int n_in,
                              void* d_out, int out_size, void* d_ws, size_t ws_size,
                              hipStream_t stream) {
  const float* x    = (const float*)d_in[0];
  const float* whg  = (const float*)d_in[1];
  const float* wout = (const float*)d_in[2];
  float* out = (float*)d_out;

  // ws (151 MB, proven-safe): [CV: M*E*4][H: M*E*2]
  unsigned int*  CV = (unsigned int*)d_ws;
  unsigned short* Hb = (unsigned short*)((char*)d_ws + (size_t)M_ * E_ * 4);
  unsigned short* Xb  = Hb;                     // bf16 X in H region until scan writes H
  unsigned short* Wb  = Xb + (size_t)M_ * D_;
  unsigned short* Wob = (unsigned short*)d_ws;  // bf16 W_out in CV region — ONLY after scans done
  // scan chunk scratch in d_out (gemm2 fully overwrites)
  float* P    = out;
  float* Qf   = out + (size_t)C_ * BE_;
  float* Qr   = out + 2 * (size_t)C_ * BE_;
  float* HfIn = out + 3 * (size_t)C_ * BE_;
  float* HbIn = out + 4 * (size_t)C_ * BE_;

  cvt_xw<<<NB_X + NB_WHG, 256, 0, stream>>>(x, Xb, whg, Wb);
  gemm1_mfma<<<dim3(M_ / 128, E_ / 64), 256, 0, stream>>>(Xb, Wb, CV, P, Qf, Qr);
  scan_p2<<<BE_ / 256, 256, 0, stream>>>(P, Qf, Qr, HfIn, HbIn);
  scan_p3<<<dim3(BE_ / 256, C_), 256, 0, stream>>>(CV, HfIn, HbIn, Hb);
  cvt_bf16<<<D_ * E_ / 1024, 256, 0, stream>>>(wout, Wob);   // CV dead now
  gemm2_mfma<<<dim3(M_ / 128, D_ / 128), 256, 0, stream>>>(Hb, Wob, out);
}